// Round 4
// baseline (479.650 us; speedup 1.0000x reference)
//
#include <hip/hip_runtime.h>

#define BB 2
#define AA 512
#define NN 1024
#define FF 64
#define DIN 128
#define DOUT 128
#define TH 25
#define ASTRIDE 40   // halves per a_tile row (16B-aligned frag base)
#define HSTRIDE 72   // halves per h_tile row (16B-aligned, 144B row pitch)
#define NSPLIT 4

typedef _Float16 half8 __attribute__((ext_vector_type(8)));
typedef float floatx4 __attribute__((ext_vector_type(4)));

__device__ __forceinline__ float ssp_f(float x) {
    return __logf(0.5f * __expf(x) + 0.5f);  // softplus(x) - ln2
}

__device__ __forceinline__ float cutcos(float r) {
    float c = 0.5f * (__cosf(r * (3.14159265358979323846f / 5.0f)) + 1.0f);
    return (r < 5.0f) ? c : 0.0f;
}

// Kernel 1: y[ba][f] = x @ W_in2f, stored f16 (one 128B line per row)
__global__ void in2f_kernel(const float* __restrict__ x,
                            const float* __restrict__ Wi,
                            _Float16* __restrict__ y) {
    __shared__ float xs[DIN];
    const int ba = blockIdx.x;
    const int t = threadIdx.x;  // 64
    xs[t] = x[ba * DIN + t];
    xs[t + 64] = x[ba * DIN + 64 + t];
    __syncthreads();
    float acc = 0.f;
#pragma unroll 8
    for (int d = 0; d < DIN; ++d) acc += xs[d] * Wi[d * FF + t];
    y[ba * FF + t] = (_Float16)acc;
}

// Kernel 2: per-(ba,split) partial of the triple MLP + gather/interp aggregation.
// grid = BB*AA*NSPLIT blocks; each wave handles 4 of the 16 tiles in its split.
__global__ __launch_bounds__(256, 4) void triple_kernel(
    const float* __restrict__ r_ij, const float* __restrict__ r_ik,
    const int* __restrict__ nbrj, const int* __restrict__ nbrk,
    const float* __restrict__ tmask, const float* __restrict__ d_ijk,
    const float* __restrict__ W_t1, const float* __restrict__ b_t1,
    const float* __restrict__ W_t2, const float* __restrict__ b_t2,
    const _Float16* __restrict__ y_tab, float* __restrict__ partial) {

    // per-wave buffers -> no __syncthreads in main loop (same-wave DS is in-order)
    __shared__ __align__(16) _Float16 a_tile[4][16 * ASTRIDE];
    __shared__ __align__(16) _Float16 h_tile[4][16 * HSTRIDE];  // h, then reused for filter
    __shared__ float red[4][FF];

    const int blk = blockIdx.x;
    const int ba = blk >> 2;
    const int split = blk & 3;
    const int b = ba >> 9;  // A = 512
    const int tid = threadIdx.x;
    const int w = tid >> 6;
    const int lane = tid & 63;
    const int quad = lane >> 4;
    const int l16 = lane & 15;
    const int rA = lane >> 3;        // row group: rows rA and rA+8
    const int fc = (lane & 7) * 8;   // feature chunk base (8 f16)

    const long ban = (long)ba * NN;
    const float* dbase = d_ijk + (long)ba * NN * TH;
    const _Float16* yb = y_tab + (long)b * (AA * FF);

    // ---- weight fragments in registers ----
    half8 B1[4];
    half8 B2[4][2];
    float b1v[4], b2v[4];
#pragma unroll
    for (int g = 0; g < 4; ++g) {
#pragma unroll
        for (int j = 0; j < 8; ++j) {
            int k = quad * 8 + j;
            B1[g][j] = (k < TH) ? (_Float16)W_t1[k * FF + g * 16 + l16]
                                : (_Float16)0.f;
        }
        b1v[g] = b_t1[g * 16 + l16];
        b2v[g] = b_t2[g * 16 + l16];
#pragma unroll
        for (int q = 0; q < 2; ++q)
#pragma unroll
            for (int j = 0; j < 8; ++j)
                B2[g][q][j] = (_Float16)W_t2[(q * 32 + quad * 8 + j) * FF + g * 16 + l16];
    }

    // zero A-tile K-pad cols 25..31 once
    for (int idx = lane; idx < 16 * 7; idx += 64) {
        int r = idx / 7, c = 25 + idx % 7;
        a_tile[w][r * ASTRIDE + c] = (_Float16)0.f;
    }

    // A staging map: 400 contiguous floats; 3 x float2/lane + 16-float tail
    int lofs2[3][2];
#pragma unroll
    for (int m = 0; m < 3; ++m)
#pragma unroll
        for (int e = 0; e < 2; ++e) {
            int s = m * 128 + lane * 2 + e;
            int r = s / TH, c = s - r * TH;
            lofs2[m][e] = r * ASTRIDE + c;
        }
    const int tofs = 15 * ASTRIDE + 9 + lane;  // tail: row 15 cols 9..24 (lane<16)

    float acc[8];
#pragma unroll
    for (int i = 0; i < 8; ++i) acc[i] = 0.f;
    const floatx4 zero4 = {0.f, 0.f, 0.f, 0.f};

    // ---- prologue: prefetch tile for it=0 ----
    float2 pA[3];
    float pT = 0.f;
    float prij0, prik0, pm0, prij1, prik1, pm1;
    int pj0, pk0, pj1, pk1;
    {
        const int n0 = (split * 16 + w) * 16;
        const float* dsrc = dbase + n0 * TH;
#pragma unroll
        for (int m = 0; m < 3; ++m) pA[m] = *(const float2*)(dsrc + m * 128 + lane * 2);
        if (lane < 16) pT = dsrc[384 + lane];
        const long n0a = ban + n0 + rA;        // row rA (8-lane broadcast line)
        const long n1a = n0a + 8;              // row rA+8
        prij0 = r_ij[n0a];  prij1 = r_ij[n1a];
        prik0 = r_ik[n0a];  prik1 = r_ik[n1a];
        pm0   = tmask[n0a]; pm1   = tmask[n1a];
        pj0   = nbrj[n0a];  pj1   = nbrj[n1a];
        pk0   = nbrk[n0a];  pk1   = nbrk[n1a];
    }

    for (int it = 0; it < NN / (16 * 4 * NSPLIT); ++it) {
        // 1. issue gathers immediately (addresses from prefetched indices)
        half8 gj0 = *(const half8*)(yb + pj0 * FF + fc);
        half8 gk0 = *(const half8*)(yb + pk0 * FF + fc);
        half8 gj1 = *(const half8*)(yb + pj1 * FF + fc);
        half8 gk1 = *(const half8*)(yb + pk1 * FF + fc);

        // 2. commit prefetched A -> LDS (f32 -> f16)
#pragma unroll
        for (int m = 0; m < 3; ++m) {
            a_tile[w][lofs2[m][0]] = (_Float16)pA[m].x;
            a_tile[w][lofs2[m][1]] = (_Float16)pA[m].y;
        }
        if (lane < 16) a_tile[w][tofs] = (_Float16)pT;

        // 3. per-lane row weights (each lane: its 2 rows)
        float c0 = cutcos(prij0) * cutcos(prik0) * pm0;
        float i0 = c0 / (prij0 + prik0);
        float wj0 = prij0 * i0, wk0 = prik0 * i0;
        float c1 = cutcos(prij1) * cutcos(prik1) * pm1;
        float i1 = c1 / (prij1 + prik1);
        float wj1 = prij1 * i1, wk1 = prik1 * i1;

        // 4. prefetch next tile (overlaps MFMA/ssp chain)
        if (it + 1 < NN / (16 * 4 * NSPLIT)) {
            const int n0 = (split * 16 + (it + 1) * 4 + w) * 16;
            const float* dn = dbase + n0 * TH;
#pragma unroll
            for (int m = 0; m < 3; ++m) pA[m] = *(const float2*)(dn + m * 128 + lane * 2);
            if (lane < 16) pT = dn[384 + lane];
            const long n0a = ban + n0 + rA;
            const long n1a = n0a + 8;
            prij0 = r_ij[n0a];  prij1 = r_ij[n1a];
            prik0 = r_ik[n0a];  prik1 = r_ik[n1a];
            pm0   = tmask[n0a]; pm1   = tmask[n1a];
            pj0   = nbrj[n0a];  pj1   = nbrj[n1a];
            pk0   = nbrk[n0a];  pk1   = nbrk[n1a];
        }

        // 5. matmul1 + ssp (A frag: m=l16, k=quad*8+j)
        half8 afrag = *(const half8*)&a_tile[w][l16 * ASTRIDE + quad * 8];
#pragma unroll
        for (int g = 0; g < 4; ++g) {
            floatx4 hv = __builtin_amdgcn_mfma_f32_16x16x32_f16(afrag, B1[g], zero4, 0, 0, 0);
#pragma unroll
            for (int r = 0; r < 4; ++r)
                h_tile[w][(quad * 4 + r) * HSTRIDE + g * 16 + l16] =
                    (_Float16)ssp_f(hv[r] + b1v[g]);
        }

        // 6. matmul2 (K=64); write filter back into h_tile (safe: reads precede
        //    writes in per-wave DS program order), read in gather layout
        half8 a2q0 = *(const half8*)&h_tile[w][l16 * HSTRIDE + quad * 8];
        half8 a2q1 = *(const half8*)&h_tile[w][l16 * HSTRIDE + 32 + quad * 8];
#pragma unroll
        for (int g = 0; g < 4; ++g) {
            floatx4 w2 = __builtin_amdgcn_mfma_f32_16x16x32_f16(a2q0, B2[g][0], zero4, 0, 0, 0);
            w2 = __builtin_amdgcn_mfma_f32_16x16x32_f16(a2q1, B2[g][1], w2, 0, 0, 0);
#pragma unroll
            for (int r = 0; r < 4; ++r)
                h_tile[w][(quad * 4 + r) * HSTRIDE + g * 16 + l16] =
                    (_Float16)(w2[r] + b2v[g]);
        }
        half8 f0 = *(const half8*)&h_tile[w][rA * HSTRIDE + fc];
        half8 f1 = *(const half8*)&h_tile[w][(8 + rA) * HSTRIDE + fc];

        // 7. epilogue: interp + accumulate (2 rows x 8 feats per lane)
#pragma unroll
        for (int i = 0; i < 8; ++i) {
            float fv0 = wj0 * (float)gj0[i] + wk0 * (float)gk0[i];
            float fv1 = wj1 * (float)gj1[i] + wk1 * (float)gk1[i];
            acc[i] += (float)f0[i] * fv0 + (float)f1[i] * fv1;
        }
    }

    // ---- reduce over row-groups within wave ----
#pragma unroll
    for (int i = 0; i < 8; ++i) {
        acc[i] += __shfl_xor(acc[i], 8, 64);
        acc[i] += __shfl_xor(acc[i], 16, 64);
        acc[i] += __shfl_xor(acc[i], 32, 64);
    }
    if (lane < 8)
#pragma unroll
        for (int i = 0; i < 8; ++i) red[w][lane * 8 + i] = acc[i];
    __syncthreads();

    if (tid < FF)
        partial[(split * (BB * AA) + ba) * FF + tid] =
            red[0][tid] + red[1][tid] + red[2][tid] + red[3][tid];
}

// Kernel 3: sum the NSPLIT partials, f2out matvec + ssp
__global__ void out_kernel(const float* __restrict__ partial,
                           const float* __restrict__ Wf,
                           const float* __restrict__ bf,
                           float* __restrict__ out) {
    __shared__ float yag[FF];
    const int ba = blockIdx.x;
    const int t = threadIdx.x;  // 128
    if (t < FF) {
        float s = 0.f;
#pragma unroll
        for (int sp = 0; sp < NSPLIT; ++sp)
            s += partial[(sp * (BB * AA) + ba) * FF + t];
        yag[t] = s;
    }
    __syncthreads();
    float a = bf[t];
#pragma unroll 8
    for (int f = 0; f < FF; ++f) a += yag[f] * Wf[f * DOUT + t];
    out[(long)ba * DOUT + t] = ssp_f(a);
}

extern "C" void kernel_launch(void* const* d_in, const int* in_sizes, int n_in,
                              void* d_out, int out_size, void* d_ws, size_t ws_size,
                              hipStream_t stream) {
    const float* x       = (const float*)d_in[0];
    const float* r_ij    = (const float*)d_in[2];
    const float* r_ik    = (const float*)d_in[3];
    const int*   nbrj    = (const int*)d_in[7];
    const int*   nbrk    = (const int*)d_in[8];
    const float* tmask   = (const float*)d_in[9];
    const float* d_ijk   = (const float*)d_in[10];
    const float* W_in2f  = (const float*)d_in[11];
    const float* W_t1    = (const float*)d_in[12];
    const float* b_t1    = (const float*)d_in[13];
    const float* W_t2    = (const float*)d_in[14];
    const float* b_t2    = (const float*)d_in[15];
    const float* W_f2out = (const float*)d_in[16];
    const float* b_f2out = (const float*)d_in[17];
    float* out = (float*)d_out;

    _Float16* y = (_Float16*)d_ws;  // BB*AA*FF halves = 128 KB
    float* partial = (float*)((char*)d_ws + (size_t)BB * AA * FF * sizeof(_Float16));
    // partial: NSPLIT * BB*AA * FF floats = 1 MB

    in2f_kernel<<<BB * AA, 64, 0, stream>>>(x, W_in2f, y);
    triple_kernel<<<BB * AA * NSPLIT, 256, 0, stream>>>(r_ij, r_ik, nbrj, nbrk,
                                                        tmask, d_ijk, W_t1, b_t1,
                                                        W_t2, b_t2, y, partial);
    out_kernel<<<BB * AA, 128, 0, stream>>>(partial, W_f2out, b_f2out, out);
}

// Round 5
// 285.006 us; speedup vs baseline: 1.6829x; 1.6829x over previous
//
#include <hip/hip_runtime.h>

#define BB 2
#define AA 512
#define NN 1024
#define FF 64
#define DIN 128
#define DOUT 128
#define TH 25
#define ASTRIDE 40   // halves per a_tile row (16B-aligned frag base)
#define HSTRIDE 72   // halves per h_tile row (16B-aligned, 144B row pitch)
#define NSPLIT 4

typedef _Float16 half8 __attribute__((ext_vector_type(8)));
typedef float floatx4 __attribute__((ext_vector_type(4)));

__device__ __forceinline__ float ssp_f(float x) {
    return __logf(0.5f * __expf(x) + 0.5f);  // softplus(x) - ln2
}

__device__ __forceinline__ float cutcos(float r) {
    float c = 0.5f * (__cosf(r * (3.14159265358979323846f / 5.0f)) + 1.0f);
    return (r < 5.0f) ? c : 0.0f;
}

// Kernel 1: y[ba][f] = x @ W_in2f, stored f16 (one 128B line per row)
__global__ void in2f_kernel(const float* __restrict__ x,
                            const float* __restrict__ Wi,
                            _Float16* __restrict__ y) {
    __shared__ float xs[DIN];
    const int ba = blockIdx.x;
    const int t = threadIdx.x;  // 64
    xs[t] = x[ba * DIN + t];
    xs[t + 64] = x[ba * DIN + 64 + t];
    __syncthreads();
    float acc = 0.f;
#pragma unroll 8
    for (int d = 0; d < DIN; ++d) acc += xs[d] * Wi[d * FF + t];
    y[ba * FF + t] = (_Float16)acc;
}

// Kernel 2: per-(ba,split) partial of the triple MLP + gather/interp aggregation.
// grid = BB*AA*NSPLIT blocks; each wave handles 4 of the 16 tiles in its split.
// NOTE: bare __launch_bounds__(256) — a (256,4) bound caps VGPRs at 64 and
// causes massive scratch spilling (measured: WRITE_SIZE 401 MB vs 1.5 MB legit).
__global__ __launch_bounds__(256) void triple_kernel(
    const float* __restrict__ r_ij, const float* __restrict__ r_ik,
    const int* __restrict__ nbrj, const int* __restrict__ nbrk,
    const float* __restrict__ tmask, const float* __restrict__ d_ijk,
    const float* __restrict__ W_t1, const float* __restrict__ b_t1,
    const float* __restrict__ W_t2, const float* __restrict__ b_t2,
    const _Float16* __restrict__ y_tab, float* __restrict__ partial) {

    // per-wave buffers -> no __syncthreads in main loop (same-wave DS is in-order)
    __shared__ __align__(16) _Float16 a_tile[4][16 * ASTRIDE];
    __shared__ __align__(16) _Float16 h_tile[4][16 * HSTRIDE];  // h, then reused for filter
    __shared__ float red[4][FF];

    const int blk = blockIdx.x;
    const int ba = blk >> 2;
    const int split = blk & 3;
    const int b = ba >> 9;  // A = 512
    const int tid = threadIdx.x;
    const int w = tid >> 6;
    const int lane = tid & 63;
    const int quad = lane >> 4;
    const int l16 = lane & 15;
    const int rA = lane >> 3;        // row group: rows rA and rA+8
    const int fc = (lane & 7) * 8;   // feature chunk base (8 f16)

    const long ban = (long)ba * NN;
    const float* dbase = d_ijk + (long)ba * NN * TH;
    const _Float16* yb = y_tab + (long)b * (AA * FF);

    // ---- weight fragments in registers ----
    half8 B1[4];
    half8 B2[4][2];
    float b1v[4], b2v[4];
#pragma unroll
    for (int g = 0; g < 4; ++g) {
#pragma unroll
        for (int j = 0; j < 8; ++j) {
            int k = quad * 8 + j;
            B1[g][j] = (k < TH) ? (_Float16)W_t1[k * FF + g * 16 + l16]
                                : (_Float16)0.f;
        }
        b1v[g] = b_t1[g * 16 + l16];
        b2v[g] = b_t2[g * 16 + l16];
#pragma unroll
        for (int q = 0; q < 2; ++q)
#pragma unroll
            for (int j = 0; j < 8; ++j)
                B2[g][q][j] = (_Float16)W_t2[(q * 32 + quad * 8 + j) * FF + g * 16 + l16];
    }

    // zero A-tile K-pad cols 25..31 once
    for (int idx = lane; idx < 16 * 7; idx += 64) {
        int r = idx / 7, c = 25 + idx % 7;
        a_tile[w][r * ASTRIDE + c] = (_Float16)0.f;
    }

    // A staging map: 400 contiguous floats; 3 x float2/lane + 16-float tail
    int lofs2[3][2];
#pragma unroll
    for (int m = 0; m < 3; ++m)
#pragma unroll
        for (int e = 0; e < 2; ++e) {
            int s = m * 128 + lane * 2 + e;
            int r = s / TH, c = s - r * TH;
            lofs2[m][e] = r * ASTRIDE + c;
        }
    const int tofs = 15 * ASTRIDE + 9 + lane;  // tail: row 15 cols 9..24 (lane<16)

    float acc[8];
#pragma unroll
    for (int i = 0; i < 8; ++i) acc[i] = 0.f;
    const floatx4 zero4 = {0.f, 0.f, 0.f, 0.f};

    // ---- prologue: prefetch tile for it=0; fold cutoffs into weights now ----
    float2 pA[3];
    float pT = 0.f;
    float pwj0, pwk0, pwj1, pwk1;
    int pj0, pk0, pj1, pk1;
    {
        const int n0 = (split * 16 + w) * 16;
        const float* dsrc = dbase + n0 * TH;
#pragma unroll
        for (int m = 0; m < 3; ++m) pA[m] = *(const float2*)(dsrc + m * 128 + lane * 2);
        if (lane < 16) pT = dsrc[384 + lane];
        const long n0a = ban + n0 + rA;        // row rA (8-lane broadcast line)
        const long n1a = n0a + 8;              // row rA+8
        float rij0 = r_ij[n0a], rij1 = r_ij[n1a];
        float rik0 = r_ik[n0a], rik1 = r_ik[n1a];
        float i0 = cutcos(rij0) * cutcos(rik0) * tmask[n0a] / (rij0 + rik0);
        float i1 = cutcos(rij1) * cutcos(rik1) * tmask[n1a] / (rij1 + rik1);
        pwj0 = rij0 * i0; pwk0 = rik0 * i0;
        pwj1 = rij1 * i1; pwk1 = rik1 * i1;
        pj0 = nbrj[n0a]; pj1 = nbrj[n1a];
        pk0 = nbrk[n0a]; pk1 = nbrk[n1a];
    }

#pragma unroll 1
    for (int it = 0; it < NN / (16 * 4 * NSPLIT); ++it) {
        // 1. issue gathers immediately (addresses from prefetched indices)
        half8 gj0 = *(const half8*)(yb + pj0 * FF + fc);
        half8 gk0 = *(const half8*)(yb + pk0 * FF + fc);
        half8 gj1 = *(const half8*)(yb + pj1 * FF + fc);
        half8 gk1 = *(const half8*)(yb + pk1 * FF + fc);
        float wj0 = pwj0, wk0 = pwk0, wj1 = pwj1, wk1 = pwk1;

        // 2. commit prefetched A -> LDS (f32 -> f16)
#pragma unroll
        for (int m = 0; m < 3; ++m) {
            a_tile[w][lofs2[m][0]] = (_Float16)pA[m].x;
            a_tile[w][lofs2[m][1]] = (_Float16)pA[m].y;
        }
        if (lane < 16) a_tile[w][tofs] = (_Float16)pT;

        // 3. prefetch next tile (overlaps MFMA/ssp chain)
        if (it + 1 < NN / (16 * 4 * NSPLIT)) {
            const int n0 = (split * 16 + (it + 1) * 4 + w) * 16;
            const float* dn = dbase + n0 * TH;
#pragma unroll
            for (int m = 0; m < 3; ++m) pA[m] = *(const float2*)(dn + m * 128 + lane * 2);
            if (lane < 16) pT = dn[384 + lane];
            const long n0a = ban + n0 + rA;
            const long n1a = n0a + 8;
            float rij0 = r_ij[n0a], rij1 = r_ij[n1a];
            float rik0 = r_ik[n0a], rik1 = r_ik[n1a];
            float i0 = cutcos(rij0) * cutcos(rik0) * tmask[n0a] / (rij0 + rik0);
            float i1 = cutcos(rij1) * cutcos(rik1) * tmask[n1a] / (rij1 + rik1);
            pwj0 = rij0 * i0; pwk0 = rik0 * i0;
            pwj1 = rij1 * i1; pwk1 = rik1 * i1;
            pj0 = nbrj[n0a]; pj1 = nbrj[n1a];
            pk0 = nbrk[n0a]; pk1 = nbrk[n1a];
        }

        // 4. matmul1 + ssp (A frag: m=l16, k=quad*8+j)
        half8 afrag = *(const half8*)&a_tile[w][l16 * ASTRIDE + quad * 8];
#pragma unroll
        for (int g = 0; g < 4; ++g) {
            floatx4 hv = __builtin_amdgcn_mfma_f32_16x16x32_f16(afrag, B1[g], zero4, 0, 0, 0);
#pragma unroll
            for (int r = 0; r < 4; ++r)
                h_tile[w][(quad * 4 + r) * HSTRIDE + g * 16 + l16] =
                    (_Float16)ssp_f(hv[r] + b1v[g]);
        }

        // 5. matmul2 (K=64); write filter back into h_tile (safe: per-wave DS
        //    program order), read back in gather layout
        half8 a2q0 = *(const half8*)&h_tile[w][l16 * HSTRIDE + quad * 8];
        half8 a2q1 = *(const half8*)&h_tile[w][l16 * HSTRIDE + 32 + quad * 8];
#pragma unroll
        for (int g = 0; g < 4; ++g) {
            floatx4 w2 = __builtin_amdgcn_mfma_f32_16x16x32_f16(a2q0, B2[g][0], zero4, 0, 0, 0);
            w2 = __builtin_amdgcn_mfma_f32_16x16x32_f16(a2q1, B2[g][1], w2, 0, 0, 0);
#pragma unroll
            for (int r = 0; r < 4; ++r)
                h_tile[w][(quad * 4 + r) * HSTRIDE + g * 16 + l16] =
                    (_Float16)(w2[r] + b2v[g]);
        }
        half8 f0 = *(const half8*)&h_tile[w][rA * HSTRIDE + fc];
        half8 f1 = *(const half8*)&h_tile[w][(8 + rA) * HSTRIDE + fc];

        // 6. epilogue: interp + accumulate (2 rows x 8 feats per lane)
#pragma unroll
        for (int i = 0; i < 8; ++i) {
            float fv0 = wj0 * (float)gj0[i] + wk0 * (float)gk0[i];
            float fv1 = wj1 * (float)gj1[i] + wk1 * (float)gk1[i];
            acc[i] += (float)f0[i] * fv0 + (float)f1[i] * fv1;
        }
    }

    // ---- reduce over row-groups within wave ----
#pragma unroll
    for (int i = 0; i < 8; ++i) {
        acc[i] += __shfl_xor(acc[i], 8, 64);
        acc[i] += __shfl_xor(acc[i], 16, 64);
        acc[i] += __shfl_xor(acc[i], 32, 64);
    }
    if (lane < 8)
#pragma unroll
        for (int i = 0; i < 8; ++i) red[w][lane * 8 + i] = acc[i];
    __syncthreads();

    if (tid < FF)
        partial[(split * (BB * AA) + ba) * FF + tid] =
            red[0][tid] + red[1][tid] + red[2][tid] + red[3][tid];
}

// Kernel 3: sum the NSPLIT partials, f2out matvec + ssp
__global__ void out_kernel(const float* __restrict__ partial,
                           const float* __restrict__ Wf,
                           const float* __restrict__ bf,
                           float* __restrict__ out) {
    __shared__ float yag[FF];
    const int ba = blockIdx.x;
    const int t = threadIdx.x;  // 128
    if (t < FF) {
        float s = 0.f;
#pragma unroll
        for (int sp = 0; sp < NSPLIT; ++sp)
            s += partial[(sp * (BB * AA) + ba) * FF + t];
        yag[t] = s;
    }
    __syncthreads();
    float a = bf[t];
#pragma unroll 8
    for (int f = 0; f < FF; ++f) a += yag[f] * Wf[f * DOUT + t];
    out[(long)ba * DOUT + t] = ssp_f(a);
}

extern "C" void kernel_launch(void* const* d_in, const int* in_sizes, int n_in,
                              void* d_out, int out_size, void* d_ws, size_t ws_size,
                              hipStream_t stream) {
    const float* x       = (const float*)d_in[0];
    const float* r_ij    = (const float*)d_in[2];
    const float* r_ik    = (const float*)d_in[3];
    const int*   nbrj    = (const int*)d_in[7];
    const int*   nbrk    = (const int*)d_in[8];
    const float* tmask   = (const float*)d_in[9];
    const float* d_ijk   = (const float*)d_in[10];
    const float* W_in2f  = (const float*)d_in[11];
    const float* W_t1    = (const float*)d_in[12];
    const float* b_t1    = (const float*)d_in[13];
    const float* W_t2    = (const float*)d_in[14];
    const float* b_t2    = (const float*)d_in[15];
    const float* W_f2out = (const float*)d_in[16];
    const float* b_f2out = (const float*)d_in[17];
    float* out = (float*)d_out;

    _Float16* y = (_Float16*)d_ws;  // BB*AA*FF halves = 128 KB
    float* partial = (float*)((char*)d_ws + (size_t)BB * AA * FF * sizeof(_Float16));
    // partial: NSPLIT * BB*AA * FF floats = 1 MB

    in2f_kernel<<<BB * AA, 64, 0, stream>>>(x, W_in2f, y);
    triple_kernel<<<BB * AA * NSPLIT, 256, 0, stream>>>(r_ij, r_ik, nbrj, nbrk,
                                                        tmask, d_ijk, W_t1, b_t1,
                                                        W_t2, b_t2, y, partial);
    out_kernel<<<BB * AA, 128, 0, stream>>>(partial, W_f2out, b_f2out, out);
}

// Round 6
// 264.571 us; speedup vs baseline: 1.8129x; 1.0772x over previous
//
#include <hip/hip_runtime.h>

#define BB 2
#define AA 512
#define NN 1024
#define FF 64
#define DIN 128
#define DOUT 128
#define TH 25
#define ASTRIDE 40   // halves per a_tile row (16B-aligned frag base)
#define HSTRIDE 72   // halves per h_tile row (16B-aligned, 144B row pitch)
#define NSPLIT 4
#define BAN_TOTAL (BB * AA * NN)

typedef _Float16 half8 __attribute__((ext_vector_type(8)));
typedef _Float16 half2v __attribute__((ext_vector_type(2)));
typedef float floatx4 __attribute__((ext_vector_type(4)));

__device__ __forceinline__ float ssp_f(float x) {
    return __logf(0.5f * __expf(x) + 0.5f);  // softplus(x) - ln2
}

__device__ __forceinline__ float cutcos(float r) {
    float c = 0.5f * (__cosf(r * (3.14159265358979323846f / 5.0f)) + 1.0f);
    return (r < 5.0f) ? c : 0.0f;
}

// ---- d_ws layout (bytes) ----
// y      : BB*AA*FF f16                 = 128 KB
// partial: NSPLIT*BB*AA*FF f32          = 1 MB
// B1tab  : 4*64*8 f16                   = 4 KB
// B2tab  : 8*64*8 f16                   = 8 KB
// bctab  : 4*64 float2                  = 2 KB
// wtab   : BAN half2                    = 4 MB
#define OFF_Y       0
#define OFF_PARTIAL (OFF_Y + (size_t)BB * AA * FF * 2)
#define OFF_B1      (OFF_PARTIAL + (size_t)NSPLIT * BB * AA * FF * 4)
#define OFF_B2      (OFF_B1 + 4 * 64 * 8 * 2)
#define OFF_BC      (OFF_B2 + 8 * 64 * 8 * 2)
#define OFF_WTAB    (OFF_BC + 4 * 64 * 8)

// Kernel 0a: pre-format MFMA weight fragments in per-lane register layout.
__global__ void prep_kernel(const float* __restrict__ W_t1, const float* __restrict__ b_t1,
                            const float* __restrict__ W_t2, const float* __restrict__ b_t2,
                            _Float16* __restrict__ B1tab, _Float16* __restrict__ B2tab,
                            float2* __restrict__ bctab) {
    const int lane = threadIdx.x;  // 64
    const int quad = lane >> 4;
    const int l16 = lane & 15;
#pragma unroll
    for (int g = 0; g < 4; ++g) {
#pragma unroll
        for (int j = 0; j < 8; ++j) {
            int k = quad * 8 + j;
            B1tab[(g * 64 + lane) * 8 + j] =
                (k < TH) ? (_Float16)W_t1[k * FF + g * 16 + l16] : (_Float16)0.f;
        }
        bctab[g * 64 + lane] = make_float2(b_t1[g * 16 + l16], b_t2[g * 16 + l16]);
#pragma unroll
        for (int q = 0; q < 2; ++q)
#pragma unroll
            for (int j = 0; j < 8; ++j)
                B2tab[((g * 2 + q) * 64 + lane) * 8 + j] =
                    (_Float16)W_t2[(q * 32 + quad * 8 + j) * FF + g * 16 + l16];
    }
}

// Kernel 0b: precompute folded interpolation weights per triple row (f16x2).
__global__ void wprep_kernel(const float* __restrict__ r_ij, const float* __restrict__ r_ik,
                             const float* __restrict__ tmask, half2v* __restrict__ wtab) {
    const int i = blockIdx.x * 256 + threadIdx.x;
    float rij = r_ij[i], rik = r_ik[i];
    float inv = cutcos(rij) * cutcos(rik) * tmask[i] / (rij + rik);
    half2v p;
    p[0] = (_Float16)(rij * inv);
    p[1] = (_Float16)(rik * inv);
    wtab[i] = p;
}

// Kernel 1: y[ba][f] = x @ W_in2f, stored f16 (one 128B line per row)
__global__ void in2f_kernel(const float* __restrict__ x,
                            const float* __restrict__ Wi,
                            _Float16* __restrict__ y) {
    __shared__ float xs[DIN];
    const int ba = blockIdx.x;
    const int t = threadIdx.x;  // 64
    xs[t] = x[ba * DIN + t];
    xs[t + 64] = x[ba * DIN + 64 + t];
    __syncthreads();
    float acc = 0.f;
#pragma unroll 8
    for (int d = 0; d < DIN; ++d) acc += xs[d] * Wi[d * FF + t];
    y[ba * FF + t] = (_Float16)acc;
}

// Kernel 2: per-(ba,split) partial of the triple MLP + gather/interp aggregation.
// NOTE: bare __launch_bounds__(256) — a (256,4) bound caps VGPRs at 64 and
// causes massive scratch spilling (measured: WRITE_SIZE 401 MB vs 1.5 MB legit).
__global__ __launch_bounds__(256) void triple_kernel(
    const int* __restrict__ nbrj, const int* __restrict__ nbrk,
    const float* __restrict__ d_ijk,
    const _Float16* __restrict__ B1tab, const _Float16* __restrict__ B2tab,
    const float2* __restrict__ bctab, const half2v* __restrict__ wtab,
    const _Float16* __restrict__ y_tab, float* __restrict__ partial) {

    // per-wave buffers -> no __syncthreads in main loop (same-wave DS is in-order)
    __shared__ __align__(16) _Float16 a_tile[4][16 * ASTRIDE];
    __shared__ __align__(16) _Float16 h_tile[4][16 * HSTRIDE];  // h, then reused for filter
    __shared__ float red[4][FF];

    const int blk = blockIdx.x;
    const int ba = blk >> 2;
    const int split = blk & 3;
    const int b = ba >> 9;  // A = 512
    const int tid = threadIdx.x;
    const int w = tid >> 6;
    const int lane = tid & 63;
    const int quad = lane >> 4;
    const int l16 = lane & 15;
    const int rA = lane >> 3;        // row group: rows rA and rA+8
    const int fc = (lane & 7) * 8;   // feature chunk base (8 f16)

    const long ban = (long)ba * NN;
    const float* dbase = d_ijk + (long)ba * NN * TH;
    const _Float16* yb = y_tab + (long)b * (AA * FF);

    // ---- weight fragments: pre-formatted, 16 vector loads ----
    half8 B1[4];
    half8 B2[4][2];
    float b1v[4], b2v[4];
#pragma unroll
    for (int g = 0; g < 4; ++g) {
        B1[g] = *(const half8*)(B1tab + (g * 64 + lane) * 8);
        B2[g][0] = *(const half8*)(B2tab + ((g * 2 + 0) * 64 + lane) * 8);
        B2[g][1] = *(const half8*)(B2tab + ((g * 2 + 1) * 64 + lane) * 8);
        float2 bc = bctab[g * 64 + lane];
        b1v[g] = bc.x;
        b2v[g] = bc.y;
    }

    // zero A-tile K-pad cols 25..31 once
    for (int idx = lane; idx < 16 * 7; idx += 64) {
        int r = idx / 7, c = 25 + idx % 7;
        a_tile[w][r * ASTRIDE + c] = (_Float16)0.f;
    }

    // A staging map: 400 contiguous floats; 3 x float2/lane + 16-float tail
    int lofs2[3][2];
#pragma unroll
    for (int m = 0; m < 3; ++m)
#pragma unroll
        for (int e = 0; e < 2; ++e) {
            int s = m * 128 + lane * 2 + e;
            int r = s / TH, c = s - r * TH;
            lofs2[m][e] = r * ASTRIDE + c;
        }
    const int tofs = 15 * ASTRIDE + 9 + lane;  // tail: row 15 cols 9..24 (lane<16)

    float acc[8];
#pragma unroll
    for (int i = 0; i < 8; ++i) acc[i] = 0.f;
    const floatx4 zero4 = {0.f, 0.f, 0.f, 0.f};

    // ---- prologue: prefetch tile for it=0 ----
    float2 pA[3];
    float pT = 0.f;
    half2v pw0, pw1;
    int pj0, pk0, pj1, pk1;
    {
        const int n0 = (split * 16 + w) * 16;
        const float* dsrc = dbase + n0 * TH;
#pragma unroll
        for (int m = 0; m < 3; ++m) pA[m] = *(const float2*)(dsrc + m * 128 + lane * 2);
        if (lane < 16) pT = dsrc[384 + lane];
        const long n0a = ban + n0 + rA;        // row rA (8-lane broadcast line)
        const long n1a = n0a + 8;              // row rA+8
        pw0 = wtab[n0a];
        pw1 = wtab[n1a];
        pj0 = nbrj[n0a]; pj1 = nbrj[n1a];
        pk0 = nbrk[n0a]; pk1 = nbrk[n1a];
    }

#pragma unroll 1
    for (int it = 0; it < NN / (16 * 4 * NSPLIT); ++it) {
        // 1. issue gathers immediately (addresses from prefetched indices)
        half8 gj0 = *(const half8*)(yb + pj0 * FF + fc);
        half8 gk0 = *(const half8*)(yb + pk0 * FF + fc);
        half8 gj1 = *(const half8*)(yb + pj1 * FF + fc);
        half8 gk1 = *(const half8*)(yb + pk1 * FF + fc);
        float wj0 = (float)pw0[0], wk0 = (float)pw0[1];
        float wj1 = (float)pw1[0], wk1 = (float)pw1[1];

        // 2. commit prefetched A -> LDS (f32 -> f16)
#pragma unroll
        for (int m = 0; m < 3; ++m) {
            a_tile[w][lofs2[m][0]] = (_Float16)pA[m].x;
            a_tile[w][lofs2[m][1]] = (_Float16)pA[m].y;
        }
        if (lane < 16) a_tile[w][tofs] = (_Float16)pT;

        // 3. prefetch next tile (overlaps MFMA/ssp chain)
        if (it + 1 < NN / (16 * 4 * NSPLIT)) {
            const int n0 = (split * 16 + (it + 1) * 4 + w) * 16;
            const float* dn = dbase + n0 * TH;
#pragma unroll
            for (int m = 0; m < 3; ++m) pA[m] = *(const float2*)(dn + m * 128 + lane * 2);
            if (lane < 16) pT = dn[384 + lane];
            const long n0a = ban + n0 + rA;
            const long n1a = n0a + 8;
            pw0 = wtab[n0a];
            pw1 = wtab[n1a];
            pj0 = nbrj[n0a]; pj1 = nbrj[n1a];
            pk0 = nbrk[n0a]; pk1 = nbrk[n1a];
        }

        // 4. matmul1 + ssp (A frag: m=l16, k=quad*8+j)
        half8 afrag = *(const half8*)&a_tile[w][l16 * ASTRIDE + quad * 8];
#pragma unroll
        for (int g = 0; g < 4; ++g) {
            floatx4 hv = __builtin_amdgcn_mfma_f32_16x16x32_f16(afrag, B1[g], zero4, 0, 0, 0);
#pragma unroll
            for (int r = 0; r < 4; ++r)
                h_tile[w][(quad * 4 + r) * HSTRIDE + g * 16 + l16] =
                    (_Float16)ssp_f(hv[r] + b1v[g]);
        }

        // 5. matmul2 (K=64); write filter back into h_tile (safe: per-wave DS
        //    program order), read back in gather layout
        half8 a2q0 = *(const half8*)&h_tile[w][l16 * HSTRIDE + quad * 8];
        half8 a2q1 = *(const half8*)&h_tile[w][l16 * HSTRIDE + 32 + quad * 8];
#pragma unroll
        for (int g = 0; g < 4; ++g) {
            floatx4 w2 = __builtin_amdgcn_mfma_f32_16x16x32_f16(a2q0, B2[g][0], zero4, 0, 0, 0);
            w2 = __builtin_amdgcn_mfma_f32_16x16x32_f16(a2q1, B2[g][1], w2, 0, 0, 0);
#pragma unroll
            for (int r = 0; r < 4; ++r)
                h_tile[w][(quad * 4 + r) * HSTRIDE + g * 16 + l16] =
                    (_Float16)(w2[r] + b2v[g]);
        }
        half8 f0 = *(const half8*)&h_tile[w][rA * HSTRIDE + fc];
        half8 f1 = *(const half8*)&h_tile[w][(8 + rA) * HSTRIDE + fc];

        // 6. epilogue: interp + accumulate (2 rows x 8 feats per lane)
#pragma unroll
        for (int i = 0; i < 8; ++i) {
            float fv0 = wj0 * (float)gj0[i] + wk0 * (float)gk0[i];
            float fv1 = wj1 * (float)gj1[i] + wk1 * (float)gk1[i];
            acc[i] += (float)f0[i] * fv0 + (float)f1[i] * fv1;
        }
    }

    // ---- reduce over row-groups within wave ----
#pragma unroll
    for (int i = 0; i < 8; ++i) {
        acc[i] += __shfl_xor(acc[i], 8, 64);
        acc[i] += __shfl_xor(acc[i], 16, 64);
        acc[i] += __shfl_xor(acc[i], 32, 64);
    }
    if (lane < 8)
#pragma unroll
        for (int i = 0; i < 8; ++i) red[w][lane * 8 + i] = acc[i];
    __syncthreads();

    if (tid < FF)
        partial[(split * (BB * AA) + ba) * FF + tid] =
            red[0][tid] + red[1][tid] + red[2][tid] + red[3][tid];
}

// Kernel 3: sum the NSPLIT partials, f2out matvec + ssp
__global__ void out_kernel(const float* __restrict__ partial,
                           const float* __restrict__ Wf,
                           const float* __restrict__ bf,
                           float* __restrict__ out) {
    __shared__ float yag[FF];
    const int ba = blockIdx.x;
    const int t = threadIdx.x;  // 128
    if (t < FF) {
        float s = 0.f;
#pragma unroll
        for (int sp = 0; sp < NSPLIT; ++sp)
            s += partial[(sp * (BB * AA) + ba) * FF + t];
        yag[t] = s;
    }
    __syncthreads();
    float a = bf[t];
#pragma unroll 8
    for (int f = 0; f < FF; ++f) a += yag[f] * Wf[f * DOUT + t];
    out[(long)ba * DOUT + t] = ssp_f(a);
}

extern "C" void kernel_launch(void* const* d_in, const int* in_sizes, int n_in,
                              void* d_out, int out_size, void* d_ws, size_t ws_size,
                              hipStream_t stream) {
    const float* x       = (const float*)d_in[0];
    const float* r_ij    = (const float*)d_in[2];
    const float* r_ik    = (const float*)d_in[3];
    const int*   nbrj    = (const int*)d_in[7];
    const int*   nbrk    = (const int*)d_in[8];
    const float* tmask   = (const float*)d_in[9];
    const float* d_ijk   = (const float*)d_in[10];
    const float* W_in2f  = (const float*)d_in[11];
    const float* W_t1    = (const float*)d_in[12];
    const float* b_t1    = (const float*)d_in[13];
    const float* W_t2    = (const float*)d_in[14];
    const float* b_t2    = (const float*)d_in[15];
    const float* W_f2out = (const float*)d_in[16];
    const float* b_f2out = (const float*)d_in[17];
    float* out = (float*)d_out;

    char* ws = (char*)d_ws;
    _Float16* y      = (_Float16*)(ws + OFF_Y);
    float* partial   = (float*)(ws + OFF_PARTIAL);
    _Float16* B1tab  = (_Float16*)(ws + OFF_B1);
    _Float16* B2tab  = (_Float16*)(ws + OFF_B2);
    float2* bctab    = (float2*)(ws + OFF_BC);
    half2v* wtab     = (half2v*)(ws + OFF_WTAB);

    prep_kernel<<<1, 64, 0, stream>>>(W_t1, b_t1, W_t2, b_t2, B1tab, B2tab, bctab);
    wprep_kernel<<<BAN_TOTAL / 256, 256, 0, stream>>>(r_ij, r_ik, tmask, wtab);
    in2f_kernel<<<BB * AA, 64, 0, stream>>>(x, W_in2f, y);
    triple_kernel<<<BB * AA * NSPLIT, 256, 0, stream>>>(nbrj, nbrk, d_ijk, B1tab,
                                                        B2tab, bctab, wtab, y, partial);
    out_kernel<<<BB * AA, 128, 0, stream>>>(partial, W_f2out, b_f2out, out);
}

// Round 8
// 259.551 us; speedup vs baseline: 1.8480x; 1.0193x over previous
//
#include <hip/hip_runtime.h>
#include <hip/hip_fp16.h>

#define BB 2
#define AA 512
#define NN 1024
#define FF 64
#define DIN 128
#define DOUT 128
#define TH 25
#define ASTRIDE 40   // halves per a_tile row (16B-aligned frag base)
#define HSTRIDE 72   // halves per h_tile row (16B-aligned, 144B row pitch)
#define NSPLIT 4

typedef _Float16 half8 __attribute__((ext_vector_type(8)));
typedef float floatx4 __attribute__((ext_vector_type(4)));

__device__ __forceinline__ float ssp_f(float x) {
    return __logf(0.5f * __expf(x) + 0.5f);  // softplus(x) - ln2
}

__device__ __forceinline__ float cutcos(float r) {
    float c = 0.5f * (__cosf(r * (3.14159265358979323846f / 5.0f)) + 1.0f);
    return (r < 5.0f) ? c : 0.0f;
}

// packed-f16 shifted softplus on a half2 (v_exp_f16/v_log_f16 + pk ops)
__device__ __forceinline__ __half2 ssp2(__half2 x) {
    const __half2 hlf = __float2half2_rn(0.5f);
    return h2log(__hfma2(h2exp(x), hlf, hlf));
}

// pack two f32 -> __half2 (v_cvt_pkrtz_f16_f32); bit-cast through memory
__device__ __forceinline__ __half2 pk2(float a, float b) {
    auto v = __builtin_amdgcn_cvt_pkrtz(a, b);  // __fp16 ext_vector(2)
    __half2 r;
    __builtin_memcpy(&r, &v, sizeof(r));
    return r;
}

// ---- d_ws layout (bytes) ----
#define OFF_Y       0                                              // 128 KB
#define OFF_PARTIAL (OFF_Y + (size_t)BB * AA * FF * 2)             // 1 MB
#define OFF_B1      (OFF_PARTIAL + (size_t)NSPLIT * BB * AA * FF * 4)
#define OFF_B2      (OFF_B1 + 4 * 64 * 8 * 2)
#define OFF_BC      (OFF_B2 + 8 * 64 * 8 * 2)

// Kernel 1: in2f (all blocks) + weight-fragment prep (block 0 only).
__global__ void in2f_prep_kernel(const float* __restrict__ x,
                                 const float* __restrict__ Wi,
                                 _Float16* __restrict__ y,
                                 const float* __restrict__ W_t1, const float* __restrict__ b_t1,
                                 const float* __restrict__ W_t2, const float* __restrict__ b_t2,
                                 _Float16* __restrict__ B1tab, _Float16* __restrict__ B2tab,
                                 float2* __restrict__ bctab) {
    __shared__ float xs[DIN];
    const int ba = blockIdx.x;
    const int t = threadIdx.x;  // 64
    xs[t] = x[ba * DIN + t];
    xs[t + 64] = x[ba * DIN + 64 + t];
    __syncthreads();
    float acc = 0.f;
#pragma unroll 8
    for (int d = 0; d < DIN; ++d) acc += xs[d] * Wi[d * FF + t];
    y[ba * FF + t] = (_Float16)acc;

    if (ba == 0) {  // prep: format MFMA B-fragments in per-lane layout
        const int lane = t, quad = t >> 4, l16 = t & 15;
#pragma unroll
        for (int g = 0; g < 4; ++g) {
#pragma unroll
            for (int j = 0; j < 8; ++j) {
                int k = quad * 8 + j;
                B1tab[(g * 64 + lane) * 8 + j] =
                    (k < TH) ? (_Float16)W_t1[k * FF + g * 16 + l16] : (_Float16)0.f;
            }
            bctab[g * 64 + lane] = make_float2(b_t1[g * 16 + l16], b_t2[g * 16 + l16]);
#pragma unroll
            for (int q = 0; q < 2; ++q)
#pragma unroll
                for (int j = 0; j < 8; ++j)
                    B2tab[((g * 2 + q) * 64 + lane) * 8 + j] =
                        (_Float16)W_t2[(q * 32 + quad * 8 + j) * FF + g * 16 + l16];
        }
    }
}

// Kernel 2: per-(ba,split) partial of the triple MLP + gather/interp aggregation.
// NOTE: bare __launch_bounds__(256) — a (256,4) bound caps VGPRs at 64 and
// causes massive scratch spilling (measured: WRITE_SIZE 401 MB vs 1.5 MB legit).
__global__ __launch_bounds__(256) void triple_kernel(
    const int* __restrict__ nbrj, const int* __restrict__ nbrk,
    const float* __restrict__ r_ij, const float* __restrict__ r_ik,
    const float* __restrict__ tmask, const float* __restrict__ d_ijk,
    const _Float16* __restrict__ B1tab, const _Float16* __restrict__ B2tab,
    const float2* __restrict__ bctab,
    const _Float16* __restrict__ y_tab, float* __restrict__ partial) {

    // per-wave buffers -> no __syncthreads in main loop (same-wave DS is in-order)
    __shared__ __align__(16) _Float16 a_tile[4][16 * ASTRIDE];
    __shared__ __align__(16) _Float16 h_tile[4][16 * HSTRIDE];  // h, then reused for filter
    __shared__ float red[4][FF];

    const int blk = blockIdx.x;
    const int ba = blk >> 2;
    const int split = blk & 3;
    const int b = ba >> 9;  // A = 512
    const int tid = threadIdx.x;
    const int w = tid >> 6;
    const int lane = tid & 63;
    const int quad = lane >> 4;
    const int l16 = lane & 15;
    const int rA = lane >> 3;        // row group: rows rA and rA+8
    const int fc = (lane & 7) * 8;   // feature chunk base (8 f16)

    const long ban = (long)ba * NN;
    const float* dbase = d_ijk + (long)ba * NN * TH;
    const _Float16* yb = y_tab + (long)b * (AA * FF);

    // ---- weight fragments: pre-formatted, 16 vector loads; biases as half2 ----
    half8 B1[4];
    half8 B2[4][2];
    __half2 b1h[4], b2h[4];
#pragma unroll
    for (int g = 0; g < 4; ++g) {
        B1[g] = *(const half8*)(B1tab + (g * 64 + lane) * 8);
        B2[g][0] = *(const half8*)(B2tab + ((g * 2 + 0) * 64 + lane) * 8);
        B2[g][1] = *(const half8*)(B2tab + ((g * 2 + 1) * 64 + lane) * 8);
        float2 bc = bctab[g * 64 + lane];
        b1h[g] = __float2half2_rn(bc.x);
        b2h[g] = __float2half2_rn(bc.y);
    }

    // zero A-tile K-pad cols 25..31 once
    for (int idx = lane; idx < 16 * 7; idx += 64) {
        int r = idx / 7, c = 25 + idx % 7;
        a_tile[w][r * ASTRIDE + c] = (_Float16)0.f;
    }

    // A staging map: 400 contiguous floats; 3 x float2/lane + 16-float tail
    int lofs2[3][2];
#pragma unroll
    for (int m = 0; m < 3; ++m)
#pragma unroll
        for (int e = 0; e < 2; ++e) {
            int s = m * 128 + lane * 2 + e;
            int r = s / TH, c = s - r * TH;
            lofs2[m][e] = r * ASTRIDE + c;
        }
    const int tofs = 15 * ASTRIDE + 9 + lane;  // tail: row 15 cols 9..24 (lane<16)

    float acc[8];
#pragma unroll
    for (int i = 0; i < 8; ++i) acc[i] = 0.f;
    const floatx4 zero4 = {0.f, 0.f, 0.f, 0.f};

    // ---- prologue: prefetch tile for it=0; fold cutoffs into f16 weights ----
    float2 pA[3];
    float pT = 0.f;
    __half2 pwj0, pwk0, pwj1, pwk1;
    int pj0, pk0, pj1, pk1;
    {
        const int n0 = (split * 16 + w) * 16;
        const float* dsrc = dbase + n0 * TH;
#pragma unroll
        for (int m = 0; m < 3; ++m) pA[m] = *(const float2*)(dsrc + m * 128 + lane * 2);
        if (lane < 16) pT = dsrc[384 + lane];
        const long n0a = ban + n0 + rA;        // row rA (8-lane broadcast line)
        const long n1a = n0a + 8;              // row rA+8
        float rij0 = r_ij[n0a], rij1 = r_ij[n1a];
        float rik0 = r_ik[n0a], rik1 = r_ik[n1a];
        float i0 = cutcos(rij0) * cutcos(rik0) * tmask[n0a] / (rij0 + rik0);
        float i1 = cutcos(rij1) * cutcos(rik1) * tmask[n1a] / (rij1 + rik1);
        pwj0 = __float2half2_rn(rij0 * i0); pwk0 = __float2half2_rn(rik0 * i0);
        pwj1 = __float2half2_rn(rij1 * i1); pwk1 = __float2half2_rn(rik1 * i1);
        pj0 = nbrj[n0a]; pj1 = nbrj[n1a];
        pk0 = nbrk[n0a]; pk1 = nbrk[n1a];
    }

#pragma unroll 1
    for (int it = 0; it < NN / (16 * 4 * NSPLIT); ++it) {
        // 1. issue gathers immediately (addresses from prefetched indices)
        half8 gj0 = *(const half8*)(yb + pj0 * FF + fc);
        half8 gk0 = *(const half8*)(yb + pk0 * FF + fc);
        half8 gj1 = *(const half8*)(yb + pj1 * FF + fc);
        half8 gk1 = *(const half8*)(yb + pk1 * FF + fc);
        __half2 wj0 = pwj0, wk0 = pwk0, wj1 = pwj1, wk1 = pwk1;

        // 2. commit prefetched A -> LDS (f32 -> f16)
#pragma unroll
        for (int m = 0; m < 3; ++m) {
            a_tile[w][lofs2[m][0]] = (_Float16)pA[m].x;
            a_tile[w][lofs2[m][1]] = (_Float16)pA[m].y;
        }
        if (lane < 16) a_tile[w][tofs] = (_Float16)pT;

        // 3. prefetch next tile (overlaps MFMA/ssp chain)
        if (it + 1 < NN / (16 * 4 * NSPLIT)) {
            const int n0 = (split * 16 + (it + 1) * 4 + w) * 16;
            const float* dn = dbase + n0 * TH;
#pragma unroll
            for (int m = 0; m < 3; ++m) pA[m] = *(const float2*)(dn + m * 128 + lane * 2);
            if (lane < 16) pT = dn[384 + lane];
            const long n0a = ban + n0 + rA;
            const long n1a = n0a + 8;
            float rij0 = r_ij[n0a], rij1 = r_ij[n1a];
            float rik0 = r_ik[n0a], rik1 = r_ik[n1a];
            float i0 = cutcos(rij0) * cutcos(rik0) * tmask[n0a] / (rij0 + rik0);
            float i1 = cutcos(rij1) * cutcos(rik1) * tmask[n1a] / (rij1 + rik1);
            pwj0 = __float2half2_rn(rij0 * i0); pwk0 = __float2half2_rn(rik0 * i0);
            pwj1 = __float2half2_rn(rij1 * i1); pwk1 = __float2half2_rn(rik1 * i1);
            pj0 = nbrj[n0a]; pj1 = nbrj[n1a];
            pk0 = nbrk[n0a]; pk1 = nbrk[n1a];
        }

        // 4. matmul1 + packed-f16 ssp (A frag: m=l16, k=quad*8+j)
        half8 afrag = *(const half8*)&a_tile[w][l16 * ASTRIDE + quad * 8];
#pragma unroll
        for (int g = 0; g < 4; ++g) {
            floatx4 hv = __builtin_amdgcn_mfma_f32_16x16x32_f16(afrag, B1[g], zero4, 0, 0, 0);
#pragma unroll
            for (int p = 0; p < 2; ++p) {  // rows quad*4+2p, +2p+1
                __half2 hh = ssp2(__hadd2(pk2(hv[2 * p], hv[2 * p + 1]), b1h[g]));
                _Float16 lo, hi;
                __builtin_memcpy(&lo, &hh, 2);
                __builtin_memcpy(&hi, (char*)&hh + 2, 2);
                h_tile[w][(quad * 4 + 2 * p) * HSTRIDE + g * 16 + l16] = lo;
                h_tile[w][(quad * 4 + 2 * p + 1) * HSTRIDE + g * 16 + l16] = hi;
            }
        }

        // 5. matmul2 (K=64); filter = w2 + b2 (packed), written back into h_tile
        //    (safe: per-wave DS program order), read back in gather layout
        half8 a2q0 = *(const half8*)&h_tile[w][l16 * HSTRIDE + quad * 8];
        half8 a2q1 = *(const half8*)&h_tile[w][l16 * HSTRIDE + 32 + quad * 8];
#pragma unroll
        for (int g = 0; g < 4; ++g) {
            floatx4 w2 = __builtin_amdgcn_mfma_f32_16x16x32_f16(a2q0, B2[g][0], zero4, 0, 0, 0);
            w2 = __builtin_amdgcn_mfma_f32_16x16x32_f16(a2q1, B2[g][1], w2, 0, 0, 0);
#pragma unroll
            for (int p = 0; p < 2; ++p) {
                __half2 fh = __hadd2(pk2(w2[2 * p], w2[2 * p + 1]), b2h[g]);
                _Float16 lo, hi;
                __builtin_memcpy(&lo, &fh, 2);
                __builtin_memcpy(&hi, (char*)&fh + 2, 2);
                h_tile[w][(quad * 4 + 2 * p) * HSTRIDE + g * 16 + l16] = lo;
                h_tile[w][(quad * 4 + 2 * p + 1) * HSTRIDE + g * 16 + l16] = hi;
            }
        }
        half8 f0 = *(const half8*)&h_tile[w][rA * HSTRIDE + fc];
        half8 f1 = *(const half8*)&h_tile[w][(8 + rA) * HSTRIDE + fc];

        // 6. epilogue: packed-f16 interp + filter-mul (2 terms only in f16),
        //    flushed to f32 accumulators every iteration
        const __half2* gj0p = (const __half2*)&gj0;
        const __half2* gk0p = (const __half2*)&gk0;
        const __half2* gj1p = (const __half2*)&gj1;
        const __half2* gk1p = (const __half2*)&gk1;
        const __half2* f0p = (const __half2*)&f0;
        const __half2* f1p = (const __half2*)&f1;
#pragma unroll
        for (int p = 0; p < 4; ++p) {
            __half2 fv0 = __hfma2(wj0, gj0p[p], __hmul2(wk0, gk0p[p]));
            __half2 fv1 = __hfma2(wj1, gj1p[p], __hmul2(wk1, gk1p[p]));
            __half2 tot = __hfma2(f1p[p], fv1, __hmul2(f0p[p], fv0));
            acc[2 * p]     += __low2float(tot);
            acc[2 * p + 1] += __high2float(tot);
        }
    }

    // ---- reduce over row-groups within wave ----
#pragma unroll
    for (int i = 0; i < 8; ++i) {
        acc[i] += __shfl_xor(acc[i], 8, 64);
        acc[i] += __shfl_xor(acc[i], 16, 64);
        acc[i] += __shfl_xor(acc[i], 32, 64);
    }
    if (lane < 8)
#pragma unroll
        for (int i = 0; i < 8; ++i) red[w][lane * 8 + i] = acc[i];
    __syncthreads();

    if (tid < FF)
        partial[(split * (BB * AA) + ba) * FF + tid] =
            red[0][tid] + red[1][tid] + red[2][tid] + red[3][tid];
}

// Kernel 3: sum the NSPLIT partials, f2out matvec + ssp
__global__ void out_kernel(const float* __restrict__ partial,
                           const float* __restrict__ Wf,
                           const float* __restrict__ bf,
                           float* __restrict__ out) {
    __shared__ float yag[FF];
    const int ba = blockIdx.x;
    const int t = threadIdx.x;  // 128
    if (t < FF) {
        float s = 0.f;
#pragma unroll
        for (int sp = 0; sp < NSPLIT; ++sp)
            s += partial[(sp * (BB * AA) + ba) * FF + t];
        yag[t] = s;
    }
    __syncthreads();
    float a = bf[t];
#pragma unroll 8
    for (int f = 0; f < FF; ++f) a += yag[f] * Wf[f * DOUT + t];
    out[(long)ba * DOUT + t] = ssp_f(a);
}

extern "C" void kernel_launch(void* const* d_in, const int* in_sizes, int n_in,
                              void* d_out, int out_size, void* d_ws, size_t ws_size,
                              hipStream_t stream) {
    const float* x       = (const float*)d_in[0];
    const float* r_ij    = (const float*)d_in[2];
    const float* r_ik    = (const float*)d_in[3];
    const int*   nbrj    = (const int*)d_in[7];
    const int*   nbrk    = (const int*)d_in[8];
    const float* tmask   = (const float*)d_in[9];
    const float* d_ijk   = (const float*)d_in[10];
    const float* W_in2f  = (const float*)d_in[11];
    const float* W_t1    = (const float*)d_in[12];
    const float* b_t1    = (const float*)d_in[13];
    const float* W_t2    = (const float*)d_in[14];
    const float* b_t2    = (const float*)d_in[15];
    const float* W_f2out = (const float*)d_in[16];
    const float* b_f2out = (const float*)d_in[17];
    float* out = (float*)d_out;

    char* ws = (char*)d_ws;
    _Float16* y      = (_Float16*)(ws + OFF_Y);
    float* partial   = (float*)(ws + OFF_PARTIAL);
    _Float16* B1tab  = (_Float16*)(ws + OFF_B1);
    _Float16* B2tab  = (_Float16*)(ws + OFF_B2);
    float2* bctab    = (float2*)(ws + OFF_BC);

    in2f_prep_kernel<<<BB * AA, 64, 0, stream>>>(x, W_in2f, y, W_t1, b_t1,
                                                 W_t2, b_t2, B1tab, B2tab, bctab);
    triple_kernel<<<BB * AA * NSPLIT, 256, 0, stream>>>(nbrj, nbrk, r_ij, r_ik,
                                                        tmask, d_ijk, B1tab, B2tab,
                                                        bctab, y, partial);
    out_kernel<<<BB * AA, 128, 0, stream>>>(partial, W_f2out, b_f2out, out);
}